// Round 1
// baseline (189.136 us; speedup 1.0000x reference)
//
#include <hip/hip_runtime.h>

// MultiHeadAttention: B=2,S=2048,D=1024,H=16,dh=64. fp32 in/out, bf16 MFMA internally.
// R8: attn_kernel pipeline overhaul (GEMMs unchanged from R7):
//  - counted-vmcnt double-buffer schedule: prefetch 2 tiles ahead, s_waitcnt vmcnt(4)
//    + raw s_barrier instead of __syncthreads (which drains vmcnt(0) every iter).
//  - XCD-grouped head mapping: 4 heads per XCD (2MB K/V -> L2-resident), t descending
//    (longest-first) for load balance.
//  - s_setprio(1) around MFMA clusters.

typedef __attribute__((ext_vector_type(8))) short short8;
typedef __attribute__((ext_vector_type(4))) float f32x4;

#define MFMA_B16(a, b, c) __builtin_amdgcn_mfma_f32_16x16x32_bf16(a, b, c, 0, 0, 0)

#if __has_builtin(__builtin_amdgcn_exp2f)
#define EXP2(x) __builtin_amdgcn_exp2f(x)
#else
#define EXP2(x) exp2f(x)
#endif

static __device__ __forceinline__ unsigned short f2bf(float f) {
    union { float f; unsigned int u; } v;
    v.f = f;
    unsigned int r = (v.u + 0x7fffu + ((v.u >> 16) & 1u)) >> 16;
    return (unsigned short)r;
}

static __device__ __forceinline__ unsigned int pk_bf16(float a, float b) {
#if __has_builtin(__builtin_amdgcn_cvt_pk_bf16_f32)
    typedef __bf16 bf2 __attribute__((ext_vector_type(2)));
    union { bf2 v; unsigned int u; } c;
    c.v = __builtin_amdgcn_cvt_pk_bf16_f32(a, b);
    return c.u;
#else
    return (unsigned int)f2bf(a) | ((unsigned int)f2bf(b) << 16);
#endif
}

static __device__ __forceinline__ void gl_lds16(const void* g, void* l) {
    __builtin_amdgcn_global_load_lds(
        (const __attribute__((address_space(1))) unsigned int*)g,
        (__attribute__((address_space(3))) unsigned int*)l, 16, 0, 0);
}

// ---------------- fused prep: convert x + transpose both weights ----------------
__global__ __launch_bounds__(256) void prep_kernel(const float4* __restrict__ x,
                                                   ushort4* __restrict__ xb,
                                                   const float* __restrict__ wqkv,
                                                   unsigned short* __restrict__ wqkvT,
                                                   const float* __restrict__ wproj,
                                                   unsigned short* __restrict__ wprojT) {
    const int bid = blockIdx.x;
    if (bid < 4096) {
        int i = bid * 256 + threadIdx.x;
        float4 v = x[i];
        ushort4 o;
        o.x = f2bf(v.x); o.y = f2bf(v.y); o.z = f2bf(v.z); o.w = f2bf(v.w);
        xb[i] = o;
        return;
    }
    __shared__ float t[32][33];
    const float* in;
    unsigned short* out;
    int R, C, bx, by;
    if (bid < 4096 + 3072) {
        int g = bid - 4096;
        in = wqkv; out = wqkvT; R = 1024; C = 3072;
        bx = g % 96; by = g / 96;
    } else {
        int g = bid - 7168;
        in = wproj; out = wprojT; R = 1024; C = 1024;
        bx = g & 31; by = g >> 5;
    }
    const int c0 = bx * 32, r0 = by * 32;
    const int xx = threadIdx.x & 31, yy0 = threadIdx.x >> 5;
    #pragma unroll
    for (int yy = yy0; yy < 32; yy += 8)
        t[yy][xx] = in[(size_t)(r0 + yy) * C + (c0 + xx)];
    __syncthreads();
    #pragma unroll
    for (int yy = yy0; yy < 32; yy += 8)
        out[(size_t)(c0 + yy) * R + (r0 + xx)] = f2bf(t[xx][yy]);
}

// ---------------- QKV GEMM: C[4096x3072] = A * Bt^T ----------------
// blockIdx.x 0..7 = Q (swapped MFMA, scaled), 8..15 = K (swapped), 16..23 = V (unswapped,
// direct b64 stores to vT [bh][d][s]).
__global__ __launch_bounds__(256) void gemm_qkv_kernel(const unsigned short* __restrict__ A,
                                                       const unsigned short* __restrict__ Bt,
                                                       const float* __restrict__ bias,
                                                       unsigned short* __restrict__ q,
                                                       unsigned short* __restrict__ k,
                                                       unsigned short* __restrict__ vT) {
    __shared__ unsigned short As[128 * 64];
    __shared__ unsigned short Bs[128 * 64];
    const int tid = threadIdx.x;
    const int lane = tid & 63, wave = tid >> 6;
    const int l15 = lane & 15, quad = lane >> 4;
    const int wm = wave >> 1, wn = wave & 1;
    const int row0 = blockIdx.y * 128, col0 = blockIdx.x * 128;
    const int K = 1024;
    const bool isV = (blockIdx.x >= 16);

    int srow[4], scol[4], sdst[4];
    #pragma unroll
    for (int h = 0; h < 4; ++h) {
        int D = h * 256 + wave * 64 + lane;
        srow[h] = D >> 3;
        scol[h] = ((D & 7) ^ (srow[h] & 7)) * 8;
        sdst[h] = (h * 256 + wave * 64) * 8;
    }

    f32x4 acc[4][4] = {};

    for (int kt = 0; kt < K; kt += 64) {
        #pragma unroll
        for (int h = 0; h < 4; ++h) {
            gl_lds16(&A[(size_t)(row0 + srow[h]) * K + kt + scol[h]], &As[sdst[h]]);
            gl_lds16(&Bt[(size_t)(col0 + srow[h]) * K + kt + scol[h]], &Bs[sdst[h]]);
        }
        __syncthreads();
        #pragma unroll
        for (int kk = 0; kk < 2; ++kk) {
            short8 af[4], bf[4];
            #pragma unroll
            for (int i = 0; i < 4; ++i) {
                int r = wm * 64 + i * 16 + l15;
                af[i] = *(const short8*)&As[r * 64 + (((kk * 4 + quad) ^ (r & 7)) * 8)];
            }
            #pragma unroll
            for (int j = 0; j < 4; ++j) {
                int r = wn * 64 + j * 16 + l15;
                bf[j] = *(const short8*)&Bs[r * 64 + (((kk * 4 + quad) ^ (r & 7)) * 8)];
            }
            if (isV) {
                #pragma unroll
                for (int i = 0; i < 4; ++i)
                    #pragma unroll
                    for (int j = 0; j < 4; ++j)
                        acc[i][j] = MFMA_B16(af[i], bf[j], acc[i][j]);  // C
            } else {
                #pragma unroll
                for (int i = 0; i < 4; ++i)
                    #pragma unroll
                    for (int j = 0; j < 4; ++j)
                        acc[i][j] = MFMA_B16(bf[j], af[i], acc[i][j]);  // C^T
            }
        }
        __syncthreads();
    }

    const int b = row0 >> 11;
    const int s0 = row0 & 2047;
    const float* bb = bias + col0 + wn * 64;

    if (!isV) {
        // C^T: lane holds d = j*16 + quad*4 + {0..3} for s = wm*64 + i*16 + l15
        const int which = blockIdx.x >> 3;  // 0=Q, 1=K
        unsigned short* dst = which ? k : q;
        const float scale = which ? 1.0f : 0.1803368867f;  // 1/8 * log2(e) for Q
        const int hh = ((blockIdx.x & 7) << 1) + wn;
        #pragma unroll
        for (int i = 0; i < 4; ++i) {
            const int s = s0 + wm * 64 + i * 16 + l15;
            unsigned short* drow = dst + ((size_t)((b * 16 + hh) * 2048 + s)) * 64;
            #pragma unroll
            for (int j = 0; j < 4; ++j) {
                float4 b4 = ((const float4*)bb)[j * 4 + quad];
                uint2 pv;
                pv.x = pk_bf16((acc[i][j][0] + b4.x) * scale, (acc[i][j][1] + b4.y) * scale);
                pv.y = pk_bf16((acc[i][j][2] + b4.z) * scale, (acc[i][j][3] + b4.w) * scale);
                *(uint2*)&drow[j * 16 + quad * 4] = pv;
            }
        }
    } else {
        // C: lane holds s = wm*64 + i*16 + quad*4 + {0..3} for d = j*16 + l15
        const int hh = ((blockIdx.x - 16) << 1) + wn;
        #pragma unroll
        for (int j = 0; j < 4; ++j) {
            const int d = j * 16 + l15;
            const float bv = bb[d];
            unsigned short* drow = vT + ((size_t)((b * 16 + hh) * 64 + d)) * 2048 + s0;
            #pragma unroll
            for (int i = 0; i < 4; ++i) {
                uint2 pv;
                pv.x = pk_bf16(acc[i][j][0] + bv, acc[i][j][1] + bv);
                pv.y = pk_bf16(acc[i][j][2] + bv, acc[i][j][3] + bv);
                *(uint2*)&drow[wm * 64 + i * 16 + quad * 4] = pv;
            }
        }
    }
}

// ---------------- proj GEMM: out[4096x1024] fp32 = A * Bt^T + bias ----------------
// Swapped MFMA -> C^T in registers -> float4 stores.
__global__ __launch_bounds__(256) void gemm_proj_kernel(const unsigned short* __restrict__ A,
                                                        const unsigned short* __restrict__ Bt,
                                                        const float* __restrict__ bias,
                                                        float* __restrict__ out) {
    __shared__ unsigned short As[128 * 64];
    __shared__ unsigned short Bs[64 * 64];
    const int tid = threadIdx.x;
    const int lane = tid & 63, wave = tid >> 6;
    const int l15 = lane & 15, quad = lane >> 4;
    const int wm = wave >> 1, wn = wave & 1;
    const int row0 = blockIdx.y * 128, col0 = blockIdx.x * 64;
    const int K = 1024;

    int srow[4], scol[4], sdst[4];
    #pragma unroll
    for (int h = 0; h < 4; ++h) {
        int D = h * 256 + wave * 64 + lane;
        srow[h] = D >> 3;
        scol[h] = ((D & 7) ^ (srow[h] & 7)) * 8;
        sdst[h] = (h * 256 + wave * 64) * 8;
    }

    f32x4 acc[4][2] = {};

    for (int kt = 0; kt < K; kt += 64) {
        #pragma unroll
        for (int h = 0; h < 4; ++h)
            gl_lds16(&A[(size_t)(row0 + srow[h]) * K + kt + scol[h]], &As[sdst[h]]);
        #pragma unroll
        for (int h = 0; h < 2; ++h)
            gl_lds16(&Bt[(size_t)(col0 + srow[h]) * K + kt + scol[h]], &Bs[sdst[h]]);
        __syncthreads();
        #pragma unroll
        for (int kk = 0; kk < 2; ++kk) {
            short8 af[4], bf[2];
            #pragma unroll
            for (int i = 0; i < 4; ++i) {
                int r = wm * 64 + i * 16 + l15;
                af[i] = *(const short8*)&As[r * 64 + (((kk * 4 + quad) ^ (r & 7)) * 8)];
            }
            #pragma unroll
            for (int j = 0; j < 2; ++j) {
                int r = wn * 32 + j * 16 + l15;
                bf[j] = *(const short8*)&Bs[r * 64 + (((kk * 4 + quad) ^ (r & 7)) * 8)];
            }
            #pragma unroll
            for (int i = 0; i < 4; ++i)
                #pragma unroll
                for (int j = 0; j < 2; ++j)
                    acc[i][j] = MFMA_B16(bf[j], af[i], acc[i][j]);  // C^T
        }
        __syncthreads();
    }

    const float* bb = bias + col0 + wn * 32;
    #pragma unroll
    for (int i = 0; i < 4; ++i) {
        const int row = row0 + wm * 64 + i * 16 + l15;
        #pragma unroll
        for (int j = 0; j < 2; ++j) {
            float4 b4 = ((const float4*)bb)[j * 4 + quad];
            float4 ov;
            ov.x = acc[i][j][0] + b4.x;
            ov.y = acc[i][j][1] + b4.y;
            ov.z = acc[i][j][2] + b4.z;
            ov.w = acc[i][j][3] + b4.w;
            *(float4*)&out[(size_t)row * 1024 + col0 + wn * 32 + j * 16 + quad * 4] = ov;
        }
    }
}

// ---------------- flash attention (R8: counted-vmcnt pipeline) ----------------
__global__ __launch_bounds__(256) void attn_kernel(const unsigned short* __restrict__ Q,
                                                   const unsigned short* __restrict__ Kg,
                                                   const unsigned short* __restrict__ Vt,
                                                   const int* __restrict__ idx,
                                                   const float* __restrict__ weight,
                                                   const int* __restrict__ forcing,
                                                   unsigned short* __restrict__ O) {
    __shared__ unsigned short Ks[2][4096];
    __shared__ unsigned short Vs[2][4096];
    __shared__ unsigned short Pw[4][1024];

    const int tid = threadIdx.x;
    const int lane = tid & 63, wave = tid >> 6;
    const int l15 = lane & 15, quad = lane >> 4;
    const int bid = blockIdx.x;
    // R8: XCD-grouped mapping. bid%8 ~ XCD (round-robin dispatch); each XCD owns
    // 4 heads -> 4 x 512KB K/V = 2MB, resident in its 4MB L2. t descending
    // (longest-first) for load balance under any dispatch order.
    const int u = bid >> 3;
    const int bh = ((bid & 7) << 2) + (u & 3);
    const int t = 31 - (u >> 2);
    const int b = bh >> 4, hh = bh & 15;
    const unsigned short* Qb = Q + (size_t)bh * 2048 * 64;
    const unsigned short* Kh = Kg + (size_t)bh * 2048 * 64;
    const unsigned short* Vh = Vt + (size_t)bh * 2048 * 64;

    const int idxb = idx[b];
    const float lw = (forcing[0] != 0) ? __log2f(weight[0]) : 0.0f;

    const int L0 = wave * 128 + lane;
    const int rS = L0 >> 3;
    const int cS = (L0 & 7) ^ (rS & 7);
    const int ldsOffJ0 = (wave * 128) * 8;
    const int ldsOffJ1 = (wave * 128 + 64) * 8;

    const int q0 = t * 64 + wave * 16;
    const int qrow = q0 + l15;

    short8 aq0 = *(const short8*)&Qb[(q0 + l15) * 64 + quad * 8];
    short8 aq1 = *(const short8*)&Qb[(q0 + l15) * 64 + 32 + quad * 8];

    const short8 ones8 = {0x3F80, 0x3F80, 0x3F80, 0x3F80, 0x3F80, 0x3F80, 0x3F80, 0x3F80};

    f32x4 o[4] = {};
    f32x4 lsum = {};

    const int nkb = t + 1;

    // R8 prologue: prefetch tiles 0 and 1 (4 gl_lds each per thread: 2 K + 2 V).
    {
        const unsigned short* kg = Kh + (size_t)rS * 64 + cS * 8;
        const unsigned short* vg = Vh + (size_t)rS * 2048 + cS * 8;
        gl_lds16(kg,            &Ks[0][ldsOffJ0]);
        gl_lds16(kg + 8 * 64,   &Ks[0][ldsOffJ1]);
        gl_lds16(vg,            &Vs[0][ldsOffJ0]);
        gl_lds16(vg + 8 * 2048, &Vs[0][ldsOffJ1]);
        if (nkb > 1) {
            gl_lds16(kg + 64 * 64,          &Ks[1][ldsOffJ0]);
            gl_lds16(kg + 64 * 64 + 8 * 64, &Ks[1][ldsOffJ1]);
            gl_lds16(vg + 64,               &Vs[1][ldsOffJ0]);
            gl_lds16(vg + 64 + 8 * 2048,    &Vs[1][ldsOffJ1]);
        }
    }

    unsigned short* const pwb = &Pw[wave][0];
    const int pwr = l15 * 64;
    const int pa7 = l15 & 7;

    for (int kb = 0; kb < nkb; ++kb) {
        const int cur = kb & 1;
        const int kbase = kb * 64;

        // R8: counted wait — tile kb's 4 loads are the oldest outstanding; leave
        // tile kb+1's 4 in flight across the whole iteration.
        if (kb + 1 < nkb) {
            asm volatile("s_waitcnt vmcnt(4)" ::: "memory");
        } else {
            asm volatile("s_waitcnt vmcnt(0)" ::: "memory");
        }
        __builtin_amdgcn_sched_barrier(0);
        __builtin_amdgcn_s_barrier();   // B1: tile kb visible to all waves
        __builtin_amdgcn_sched_barrier(0);

        const bool fullF = (kbase >= idxb);
        const bool bndF = (!fullF) && (kbase + 63 >= idxb);
        const float zu = fullF ? lw : 0.0f;

        f32x4 sT[4];
        #pragma unroll
        for (int kt = 0; kt < 4; ++kt) {
            const int row = kt * 16 + l15;
            short8 k0 = *(const short8*)&Ks[cur][row * 64 + ((quad ^ (row & 7)) * 8)];
            short8 k1 = *(const short8*)&Ks[cur][row * 64 + (((4 + quad) ^ (row & 7)) * 8)];
            f32x4 z;
            if (!bndF) {
                z[0] = zu; z[1] = zu; z[2] = zu; z[3] = zu;
            } else {
                #pragma unroll
                for (int r = 0; r < 4; ++r)
                    z[r] = (kbase + kt * 16 + quad * 4 + r >= idxb) ? lw : 0.0f;
            }
            __builtin_amdgcn_s_setprio(1);
            z = MFMA_B16(k0, aq0, z);
            z = MFMA_B16(k1, aq1, z);
            __builtin_amdgcn_s_setprio(0);
            sT[kt] = z;
        }

        if (kb == t) {
            #pragma unroll
            for (int kt = 0; kt < 4; ++kt)
                #pragma unroll
                for (int r = 0; r < 4; ++r)
                    if (kbase + kt * 16 + quad * 4 + r > qrow) sT[kt][r] = -3.0e38f;
        }

        #pragma unroll
        for (int kt = 0; kt < 4; ++kt)
            #pragma unroll
            for (int r = 0; r < 4; ++r)
                sT[kt][r] = EXP2(sT[kt][r]);

        #pragma unroll
        for (int kt = 0; kt < 4; ++kt) {
            unsigned int* pw = (unsigned int*)&pwb[pwr +
                (((kt * 2 + (quad >> 1)) ^ pa7) * 8) + (quad & 1) * 4];
            pw[0] = pk_bf16(sT[kt][0], sT[kt][1]);
            pw[1] = pk_bf16(sT[kt][2], sT[kt][3]);
        }

        short8 bp0 = *(const short8*)&pwb[pwr + ((quad ^ pa7) * 8)];
        short8 bp1 = *(const short8*)&pwb[pwr + (((4 + quad) ^ pa7) * 8)];

        __builtin_amdgcn_s_setprio(1);
        lsum = MFMA_B16(ones8, bp0, lsum);
        lsum = MFMA_B16(ones8, bp1, lsum);
        __builtin_amdgcn_s_setprio(0);

        #pragma unroll
        for (int dt = 0; dt < 4; ++dt) {
            const int row = dt * 16 + l15;
            short8 vf0 = *(const short8*)&Vs[cur][row * 64 + ((quad ^ (row & 7)) * 8)];
            short8 vf1 = *(const short8*)&Vs[cur][row * 64 + (((4 + quad) ^ (row & 7)) * 8)];
            f32x4 oo = o[dt];
            __builtin_amdgcn_s_setprio(1);
            oo = MFMA_B16(vf0, bp0, oo);
            oo = MFMA_B16(vf1, bp1, oo);
            __builtin_amdgcn_s_setprio(0);
            o[dt] = oo;
        }

        // R8: B2 — all waves done reading buf[cur]; then refill it with tile kb+2.
        asm volatile("s_waitcnt lgkmcnt(0)" ::: "memory");
        __builtin_amdgcn_sched_barrier(0);
        __builtin_amdgcn_s_barrier();
        __builtin_amdgcn_sched_barrier(0);

        if (kb + 2 < nkb) {
            const int nb = kbase + 128;
            const unsigned short* kg = Kh + (size_t)(nb + rS) * 64 + cS * 8;
            const unsigned short* vg = Vh + (size_t)rS * 2048 + nb + cS * 8;
            gl_lds16(kg,            &Ks[cur][ldsOffJ0]);
            gl_lds16(kg + 8 * 64,   &Ks[cur][ldsOffJ1]);
            gl_lds16(vg,            &Vs[cur][ldsOffJ0]);
            gl_lds16(vg + 8 * 2048, &Vs[cur][ldsOffJ1]);
        }
    }

    const float inv = 1.0f / lsum[0];
    unsigned short* sc = &Ks[0][0] + wave * 1152;
    #pragma unroll
    for (int dt = 0; dt < 4; ++dt)
        #pragma unroll
        for (int r = 0; r < 4; ++r)
            sc[l15 * 72 + dt * 16 + quad * 4 + r] = f2bf(o[dt][r] * inv);
    const size_t rowoff = ((size_t)(b * 2048 + q0 + l15)) * 1024 + hh * 64;
    #pragma unroll
    for (int h = 0; h < 2; ++h) {
        short8 v8 = *(const short8*)&sc[l15 * 72 + quad * 16 + h * 8];
        *(short8*)&O[rowoff + quad * 16 + h * 8] = v8;
    }
}

extern "C" void kernel_launch(void* const* d_in, const int* in_sizes, int n_in,
                              void* d_out, int out_size, void* d_ws, size_t ws_size,
                              hipStream_t stream) {
    const float* x        = (const float*)d_in[0];
    const int*   idx      = (const int*)d_in[1];
    const float* weight   = (const float*)d_in[2];
    const int*   forcing  = (const int*)d_in[3];
    const float* w_qkv    = (const float*)d_in[4];
    const float* b_qkv    = (const float*)d_in[5];
    const float* w_proj   = (const float*)d_in[6];
    const float* b_proj   = (const float*)d_in[7];
    float* out = (float*)d_out;

    char* ws = (char*)d_ws;
    unsigned short* xb      = (unsigned short*)(ws);              // 8 MB (reused: attn_out)
    unsigned short* wqkvT   = (unsigned short*)(ws + 8388608);    // 6 MB
    unsigned short* wprojT  = (unsigned short*)(ws + 14680064);   // 2 MB
    unsigned short* qbuf    = (unsigned short*)(ws + 16777216);   // 8 MB
    unsigned short* kbuf    = (unsigned short*)(ws + 25165824);   // 8 MB
    unsigned short* vTbuf   = (unsigned short*)(ws + 33554432);   // 8 MB
    unsigned short* attn_out = xb;  // xb dead after gemm_qkv

    prep_kernel<<<8192, 256, 0, stream>>>((const float4*)x, (ushort4*)xb,
                                          w_qkv, wqkvT, w_proj, wprojT);
    gemm_qkv_kernel<<<dim3(24, 32), 256, 0, stream>>>(xb, wqkvT, b_qkv, qbuf, kbuf, vTbuf);
    attn_kernel<<<1024, 256, 0, stream>>>(qbuf, kbuf, vTbuf, idx, weight, forcing, attn_out);
    gemm_proj_kernel<<<dim3(16, 32), 256, 0, stream>>>(attn_out, wprojT, b_proj, out);
}

// Round 2
// 188.259 us; speedup vs baseline: 1.0047x; 1.0047x over previous
//
#include <hip/hip_runtime.h>

// MultiHeadAttention: B=2,S=2048,D=1024,H=16,dh=64. fp32 in/out, bf16 MFMA internally.
// R9: attn_kernel balanced-pair merge (GEMMs unchanged from R7):
//  - one 512-thread block handles the causal pair of q-tiles (tA=31-p, tB=p): waves 0-3
//    compute tA, waves 4-7 compute tB, sharing one K/V LDS staging stream. Per-block
//    work is constant (33 wave-iterations) -> perfect balance, 2 blocks/CU, 16 waves/CU.
//  - schedule reverted to proven R7 form: prefetch at loop top, single __syncthreads
//    per iteration (R8's raw-barrier/counted-vmcnt/setprio/sched_barrier removed —
//    it regressed 43.7->50.9 us).
//  - XCD-grouped heads: bid&7 ~ XCD, 4 heads per XCD (2MB K/V, L2-resident).

typedef __attribute__((ext_vector_type(8))) short short8;
typedef __attribute__((ext_vector_type(4))) float f32x4;

#define MFMA_B16(a, b, c) __builtin_amdgcn_mfma_f32_16x16x32_bf16(a, b, c, 0, 0, 0)

#if __has_builtin(__builtin_amdgcn_exp2f)
#define EXP2(x) __builtin_amdgcn_exp2f(x)
#else
#define EXP2(x) exp2f(x)
#endif

static __device__ __forceinline__ unsigned short f2bf(float f) {
    union { float f; unsigned int u; } v;
    v.f = f;
    unsigned int r = (v.u + 0x7fffu + ((v.u >> 16) & 1u)) >> 16;
    return (unsigned short)r;
}

static __device__ __forceinline__ unsigned int pk_bf16(float a, float b) {
#if __has_builtin(__builtin_amdgcn_cvt_pk_bf16_f32)
    typedef __bf16 bf2 __attribute__((ext_vector_type(2)));
    union { bf2 v; unsigned int u; } c;
    c.v = __builtin_amdgcn_cvt_pk_bf16_f32(a, b);
    return c.u;
#else
    return (unsigned int)f2bf(a) | ((unsigned int)f2bf(b) << 16);
#endif
}

static __device__ __forceinline__ void gl_lds16(const void* g, void* l) {
    __builtin_amdgcn_global_load_lds(
        (const __attribute__((address_space(1))) unsigned int*)g,
        (__attribute__((address_space(3))) unsigned int*)l, 16, 0, 0);
}

// ---------------- fused prep: convert x + transpose both weights ----------------
__global__ __launch_bounds__(256) void prep_kernel(const float4* __restrict__ x,
                                                   ushort4* __restrict__ xb,
                                                   const float* __restrict__ wqkv,
                                                   unsigned short* __restrict__ wqkvT,
                                                   const float* __restrict__ wproj,
                                                   unsigned short* __restrict__ wprojT) {
    const int bid = blockIdx.x;
    if (bid < 4096) {
        int i = bid * 256 + threadIdx.x;
        float4 v = x[i];
        ushort4 o;
        o.x = f2bf(v.x); o.y = f2bf(v.y); o.z = f2bf(v.z); o.w = f2bf(v.w);
        xb[i] = o;
        return;
    }
    __shared__ float t[32][33];
    const float* in;
    unsigned short* out;
    int R, C, bx, by;
    if (bid < 4096 + 3072) {
        int g = bid - 4096;
        in = wqkv; out = wqkvT; R = 1024; C = 3072;
        bx = g % 96; by = g / 96;
    } else {
        int g = bid - 7168;
        in = wproj; out = wprojT; R = 1024; C = 1024;
        bx = g & 31; by = g >> 5;
    }
    const int c0 = bx * 32, r0 = by * 32;
    const int xx = threadIdx.x & 31, yy0 = threadIdx.x >> 5;
    #pragma unroll
    for (int yy = yy0; yy < 32; yy += 8)
        t[yy][xx] = in[(size_t)(r0 + yy) * C + (c0 + xx)];
    __syncthreads();
    #pragma unroll
    for (int yy = yy0; yy < 32; yy += 8)
        out[(size_t)(c0 + yy) * R + (r0 + xx)] = f2bf(t[xx][yy]);
}

// ---------------- QKV GEMM: C[4096x3072] = A * Bt^T ----------------
// blockIdx.x 0..7 = Q (swapped MFMA, scaled), 8..15 = K (swapped), 16..23 = V (unswapped,
// direct b64 stores to vT [bh][d][s]).
__global__ __launch_bounds__(256) void gemm_qkv_kernel(const unsigned short* __restrict__ A,
                                                       const unsigned short* __restrict__ Bt,
                                                       const float* __restrict__ bias,
                                                       unsigned short* __restrict__ q,
                                                       unsigned short* __restrict__ k,
                                                       unsigned short* __restrict__ vT) {
    __shared__ unsigned short As[128 * 64];
    __shared__ unsigned short Bs[128 * 64];
    const int tid = threadIdx.x;
    const int lane = tid & 63, wave = tid >> 6;
    const int l15 = lane & 15, quad = lane >> 4;
    const int wm = wave >> 1, wn = wave & 1;
    const int row0 = blockIdx.y * 128, col0 = blockIdx.x * 128;
    const int K = 1024;
    const bool isV = (blockIdx.x >= 16);

    int srow[4], scol[4], sdst[4];
    #pragma unroll
    for (int h = 0; h < 4; ++h) {
        int D = h * 256 + wave * 64 + lane;
        srow[h] = D >> 3;
        scol[h] = ((D & 7) ^ (srow[h] & 7)) * 8;
        sdst[h] = (h * 256 + wave * 64) * 8;
    }

    f32x4 acc[4][4] = {};

    for (int kt = 0; kt < K; kt += 64) {
        #pragma unroll
        for (int h = 0; h < 4; ++h) {
            gl_lds16(&A[(size_t)(row0 + srow[h]) * K + kt + scol[h]], &As[sdst[h]]);
            gl_lds16(&Bt[(size_t)(col0 + srow[h]) * K + kt + scol[h]], &Bs[sdst[h]]);
        }
        __syncthreads();
        #pragma unroll
        for (int kk = 0; kk < 2; ++kk) {
            short8 af[4], bf[4];
            #pragma unroll
            for (int i = 0; i < 4; ++i) {
                int r = wm * 64 + i * 16 + l15;
                af[i] = *(const short8*)&As[r * 64 + (((kk * 4 + quad) ^ (r & 7)) * 8)];
            }
            #pragma unroll
            for (int j = 0; j < 4; ++j) {
                int r = wn * 64 + j * 16 + l15;
                bf[j] = *(const short8*)&Bs[r * 64 + (((kk * 4 + quad) ^ (r & 7)) * 8)];
            }
            if (isV) {
                #pragma unroll
                for (int i = 0; i < 4; ++i)
                    #pragma unroll
                    for (int j = 0; j < 4; ++j)
                        acc[i][j] = MFMA_B16(af[i], bf[j], acc[i][j]);  // C
            } else {
                #pragma unroll
                for (int i = 0; i < 4; ++i)
                    #pragma unroll
                    for (int j = 0; j < 4; ++j)
                        acc[i][j] = MFMA_B16(bf[j], af[i], acc[i][j]);  // C^T
            }
        }
        __syncthreads();
    }

    const int b = row0 >> 11;
    const int s0 = row0 & 2047;
    const float* bb = bias + col0 + wn * 64;

    if (!isV) {
        // C^T: lane holds d = j*16 + quad*4 + {0..3} for s = wm*64 + i*16 + l15
        const int which = blockIdx.x >> 3;  // 0=Q, 1=K
        unsigned short* dst = which ? k : q;
        const float scale = which ? 1.0f : 0.1803368867f;  // 1/8 * log2(e) for Q
        const int hh = ((blockIdx.x & 7) << 1) + wn;
        #pragma unroll
        for (int i = 0; i < 4; ++i) {
            const int s = s0 + wm * 64 + i * 16 + l15;
            unsigned short* drow = dst + ((size_t)((b * 16 + hh) * 2048 + s)) * 64;
            #pragma unroll
            for (int j = 0; j < 4; ++j) {
                float4 b4 = ((const float4*)bb)[j * 4 + quad];
                uint2 pv;
                pv.x = pk_bf16((acc[i][j][0] + b4.x) * scale, (acc[i][j][1] + b4.y) * scale);
                pv.y = pk_bf16((acc[i][j][2] + b4.z) * scale, (acc[i][j][3] + b4.w) * scale);
                *(uint2*)&drow[j * 16 + quad * 4] = pv;
            }
        }
    } else {
        // C: lane holds s = wm*64 + i*16 + quad*4 + {0..3} for d = j*16 + l15
        const int hh = ((blockIdx.x - 16) << 1) + wn;
        #pragma unroll
        for (int j = 0; j < 4; ++j) {
            const int d = j * 16 + l15;
            const float bv = bb[d];
            unsigned short* drow = vT + ((size_t)((b * 16 + hh) * 64 + d)) * 2048 + s0;
            #pragma unroll
            for (int i = 0; i < 4; ++i) {
                uint2 pv;
                pv.x = pk_bf16(acc[i][j][0] + bv, acc[i][j][1] + bv);
                pv.y = pk_bf16(acc[i][j][2] + bv, acc[i][j][3] + bv);
                *(uint2*)&drow[wm * 64 + i * 16 + quad * 4] = pv;
            }
        }
    }
}

// ---------------- proj GEMM: out[4096x1024] fp32 = A * Bt^T + bias ----------------
// Swapped MFMA -> C^T in registers -> float4 stores.
__global__ __launch_bounds__(256) void gemm_proj_kernel(const unsigned short* __restrict__ A,
                                                        const unsigned short* __restrict__ Bt,
                                                        const float* __restrict__ bias,
                                                        float* __restrict__ out) {
    __shared__ unsigned short As[128 * 64];
    __shared__ unsigned short Bs[64 * 64];
    const int tid = threadIdx.x;
    const int lane = tid & 63, wave = tid >> 6;
    const int l15 = lane & 15, quad = lane >> 4;
    const int wm = wave >> 1, wn = wave & 1;
    const int row0 = blockIdx.y * 128, col0 = blockIdx.x * 64;
    const int K = 1024;

    int srow[4], scol[4], sdst[4];
    #pragma unroll
    for (int h = 0; h < 4; ++h) {
        int D = h * 256 + wave * 64 + lane;
        srow[h] = D >> 3;
        scol[h] = ((D & 7) ^ (srow[h] & 7)) * 8;
        sdst[h] = (h * 256 + wave * 64) * 8;
    }

    f32x4 acc[4][2] = {};

    for (int kt = 0; kt < K; kt += 64) {
        #pragma unroll
        for (int h = 0; h < 4; ++h)
            gl_lds16(&A[(size_t)(row0 + srow[h]) * K + kt + scol[h]], &As[sdst[h]]);
        #pragma unroll
        for (int h = 0; h < 2; ++h)
            gl_lds16(&Bt[(size_t)(col0 + srow[h]) * K + kt + scol[h]], &Bs[sdst[h]]);
        __syncthreads();
        #pragma unroll
        for (int kk = 0; kk < 2; ++kk) {
            short8 af[4], bf[2];
            #pragma unroll
            for (int i = 0; i < 4; ++i) {
                int r = wm * 64 + i * 16 + l15;
                af[i] = *(const short8*)&As[r * 64 + (((kk * 4 + quad) ^ (r & 7)) * 8)];
            }
            #pragma unroll
            for (int j = 0; j < 2; ++j) {
                int r = wn * 32 + j * 16 + l15;
                bf[j] = *(const short8*)&Bs[r * 64 + (((kk * 4 + quad) ^ (r & 7)) * 8)];
            }
            #pragma unroll
            for (int i = 0; i < 4; ++i)
                #pragma unroll
                for (int j = 0; j < 2; ++j)
                    acc[i][j] = MFMA_B16(bf[j], af[i], acc[i][j]);  // C^T
        }
        __syncthreads();
    }

    const float* bb = bias + col0 + wn * 32;
    #pragma unroll
    for (int i = 0; i < 4; ++i) {
        const int row = row0 + wm * 64 + i * 16 + l15;
        #pragma unroll
        for (int j = 0; j < 2; ++j) {
            float4 b4 = ((const float4*)bb)[j * 4 + quad];
            float4 ov;
            ov.x = acc[i][j][0] + b4.x;
            ov.y = acc[i][j][1] + b4.y;
            ov.z = acc[i][j][2] + b4.z;
            ov.w = acc[i][j][3] + b4.w;
            *(float4*)&out[(size_t)row * 1024 + col0 + wn * 32 + j * 16 + quad * 4] = ov;
        }
    }
}

// ---------------- flash attention (R9: balanced-pair 512-thread blocks) ----------------
// smem layout (shorts): [0..4095] Ks0 | [4096..8191] Ks1 | [8192..12287] Vs0
//                       [12288..16383] Vs1 | [16384..24575] Pw[8][1024]
__global__ __launch_bounds__(512) void attn_kernel(const unsigned short* __restrict__ Q,
                                                   const unsigned short* __restrict__ Kg,
                                                   const unsigned short* __restrict__ Vt,
                                                   const int* __restrict__ idx,
                                                   const float* __restrict__ weight,
                                                   const int* __restrict__ forcing,
                                                   unsigned short* __restrict__ O) {
    __shared__ unsigned short smem[24576];

    const int tid = threadIdx.x;
    const int lane = tid & 63, wave = tid >> 6;
    const int l15 = lane & 15, quad = lane >> 4;
    const int bid = blockIdx.x;
    // 512 blocks: bid&7 ~ XCD (round-robin dispatch) -> 4 heads per XCD (2MB K/V in L2).
    const int g = bid >> 3;
    const int bh = ((bid & 7) << 2) + (g & 3);
    const int p = g >> 2;             // pair index 0..15
    const int tA = 31 - p, tB = p;    // paired q-tiles: (tA+1)+(tB+1) = 33 = const work
    const int b = bh >> 4, hh = bh & 15;
    const unsigned short* Qb = Q + (size_t)bh * 2048 * 64;
    const unsigned short* Kh = Kg + (size_t)bh * 2048 * 64;
    const unsigned short* Vh = Vt + (size_t)bh * 2048 * 64;

    const int idxb = idx[b];
    const float lw = (forcing[0] != 0) ? __log2f(weight[0]) : 0.0f;

    // this wave's q-tile: waves 0-3 -> tA, waves 4-7 -> tB
    const int wq = (wave < 4) ? tA : tB;
    const int wg = wave & 3;
    const int q0 = wq * 64 + wg * 16;
    const int qrow = q0 + l15;
    const int nkb = tA + 1;    // block-level k-tile count
    const int nkbw = wq + 1;   // this wave's active k-tile count

    // staging: 512 threads, 1 K-chunk + 1 V-chunk (16B) each per tile
    const int rS = tid >> 3;
    const int cS8 = ((tid & 7) ^ (rS & 7)) * 8;

    short8 aq0 = *(const short8*)&Qb[(q0 + l15) * 64 + quad * 8];
    short8 aq1 = *(const short8*)&Qb[(q0 + l15) * 64 + 32 + quad * 8];

    const short8 ones8 = {0x3F80, 0x3F80, 0x3F80, 0x3F80, 0x3F80, 0x3F80, 0x3F80, 0x3F80};

    f32x4 o[4] = {};
    f32x4 lsum = {};

    // prologue: stage tile 0
    gl_lds16(Kh + (size_t)rS * 64 + cS8,   &smem[tid * 8]);
    gl_lds16(Vh + (size_t)rS * 2048 + cS8, &smem[8192 + tid * 8]);
    __syncthreads();

    unsigned short* const pwb = &smem[16384 + wave * 1024];
    const int pwr = l15 * 64;
    const int pa7 = l15 & 7;

    for (int kb = 0; kb < nkb; ++kb) {
        const int cur = kb & 1;
        const int kbase = kb * 64;
        if (kb + 1 < nkb) {
            const int nb = kbase + 64;
            gl_lds16(Kh + (size_t)(nb + rS) * 64 + cS8,      &smem[(cur ^ 1) * 4096 + tid * 8]);
            gl_lds16(Vh + (size_t)rS * 2048 + nb + cS8,      &smem[8192 + (cur ^ 1) * 4096 + tid * 8]);
        }

        if (kb < nkbw) {
            const unsigned short* KsP = &smem[cur * 4096];
            const unsigned short* VsP = &smem[8192 + cur * 4096];

            const bool fullF = (kbase >= idxb);
            const bool bndF = (!fullF) && (kbase + 63 >= idxb);
            const float zu = fullF ? lw : 0.0f;

            f32x4 sT[4];
            #pragma unroll
            for (int kt = 0; kt < 4; ++kt) {
                const int row = kt * 16 + l15;
                short8 k0 = *(const short8*)&KsP[row * 64 + ((quad ^ (row & 7)) * 8)];
                short8 k1 = *(const short8*)&KsP[row * 64 + (((4 + quad) ^ (row & 7)) * 8)];
                f32x4 z;
                if (!bndF) {
                    z[0] = zu; z[1] = zu; z[2] = zu; z[3] = zu;
                } else {
                    #pragma unroll
                    for (int r = 0; r < 4; ++r)
                        z[r] = (kbase + kt * 16 + quad * 4 + r >= idxb) ? lw : 0.0f;
                }
                z = MFMA_B16(k0, aq0, z);
                z = MFMA_B16(k1, aq1, z);
                sT[kt] = z;
            }

            if (kb == wq) {
                #pragma unroll
                for (int kt = 0; kt < 4; ++kt)
                    #pragma unroll
                    for (int r = 0; r < 4; ++r)
                        if (kbase + kt * 16 + quad * 4 + r > qrow) sT[kt][r] = -3.0e38f;
            }

            #pragma unroll
            for (int kt = 0; kt < 4; ++kt)
                #pragma unroll
                for (int r = 0; r < 4; ++r)
                    sT[kt][r] = EXP2(sT[kt][r]);

            #pragma unroll
            for (int kt = 0; kt < 4; ++kt) {
                unsigned int* pw = (unsigned int*)&pwb[pwr +
                    (((kt * 2 + (quad >> 1)) ^ pa7) * 8) + (quad & 1) * 4];
                pw[0] = pk_bf16(sT[kt][0], sT[kt][1]);
                pw[1] = pk_bf16(sT[kt][2], sT[kt][3]);
            }

            short8 bp0 = *(const short8*)&pwb[pwr + ((quad ^ pa7) * 8)];
            short8 bp1 = *(const short8*)&pwb[pwr + (((4 + quad) ^ pa7) * 8)];

            lsum = MFMA_B16(ones8, bp0, lsum);
            lsum = MFMA_B16(ones8, bp1, lsum);

            #pragma unroll
            for (int dt = 0; dt < 4; ++dt) {
                const int row = dt * 16 + l15;
                short8 vf0 = *(const short8*)&VsP[row * 64 + ((quad ^ (row & 7)) * 8)];
                short8 vf1 = *(const short8*)&VsP[row * 64 + (((4 + quad) ^ (row & 7)) * 8)];
                f32x4 oo = o[dt];
                oo = MFMA_B16(vf0, bp0, oo);
                oo = MFMA_B16(vf1, bp1, oo);
                o[dt] = oo;
            }
        }

        __syncthreads();
    }

    // epilogue: per-wave transpose through LDS scratch (8 waves x 1152 shorts <= 24576)
    const float inv = 1.0f / lsum[0];
    unsigned short* sc = &smem[wave * 1152];
    #pragma unroll
    for (int dt = 0; dt < 4; ++dt)
        #pragma unroll
        for (int r = 0; r < 4; ++r)
            sc[l15 * 72 + dt * 16 + quad * 4 + r] = f2bf(o[dt][r] * inv);
    const size_t rowoff = ((size_t)(b * 2048 + q0 + l15)) * 1024 + hh * 64;
    #pragma unroll
    for (int h = 0; h < 2; ++h) {
        short8 v8 = *(const short8*)&sc[l15 * 72 + quad * 16 + h * 8];
        *(short8*)&O[rowoff + quad * 16 + h * 8] = v8;
    }
}

extern "C" void kernel_launch(void* const* d_in, const int* in_sizes, int n_in,
                              void* d_out, int out_size, void* d_ws, size_t ws_size,
                              hipStream_t stream) {
    const float* x        = (const float*)d_in[0];
    const int*   idx      = (const int*)d_in[1];
    const float* weight   = (const float*)d_in[2];
    const int*   forcing  = (const int*)d_in[3];
    const float* w_qkv    = (const float*)d_in[4];
    const float* b_qkv    = (const float*)d_in[5];
    const float* w_proj   = (const float*)d_in[6];
    const float* b_proj   = (const float*)d_in[7];
    float* out = (float*)d_out;

    char* ws = (char*)d_ws;
    unsigned short* xb      = (unsigned short*)(ws);              // 8 MB (reused: attn_out)
    unsigned short* wqkvT   = (unsigned short*)(ws + 8388608);    // 6 MB
    unsigned short* wprojT  = (unsigned short*)(ws + 14680064);   // 2 MB
    unsigned short* qbuf    = (unsigned short*)(ws + 16777216);   // 8 MB
    unsigned short* kbuf    = (unsigned short*)(ws + 25165824);   // 8 MB
    unsigned short* vTbuf   = (unsigned short*)(ws + 33554432);   // 8 MB
    unsigned short* attn_out = xb;  // xb dead after gemm_qkv

    prep_kernel<<<8192, 256, 0, stream>>>((const float4*)x, (ushort4*)xb,
                                          w_qkv, wqkvT, w_proj, wprojT);
    gemm_qkv_kernel<<<dim3(24, 32), 256, 0, stream>>>(xb, wqkvT, b_qkv, qbuf, kbuf, vTbuf);
    attn_kernel<<<512, 512, 0, stream>>>(qbuf, kbuf, vTbuf, idx, weight, forcing, attn_out);
    gemm_proj_kernel<<<dim3(16, 32), 256, 0, stream>>>(attn_out, wprojT, b_proj, out);
}

// Round 3
// 183.274 us; speedup vs baseline: 1.0320x; 1.0272x over previous
//
#include <hip/hip_runtime.h>

// MultiHeadAttention: B=2,S=2048,D=1024,H=16,dh=64. fp32 in/out, bf16 MFMA internally.
// R10: attn_kernel adjacent-pair blocks (GEMMs unchanged from R7):
//  - block handles q-tiles (tA=2p+1, tB=2p): waves 0-3 -> tA (active all 2p+2 tiles),
//    waves 4-7 -> tB (idle only on the final diagonal tile). Block runtime = 2p+2
//    iters; per-bh iteration total drops 392 -> 272 vs R9's complementary pairing
//    (where waves 4-7 spun for up to 31 tiles).
//  - makespan pairing: bid<256 carries long blocks (p=8..15), bid>=256 the complement
//    (p=7..0) with identical rem -> each CU's 2 resident blocks sum to 34 iters AND
//    stream the same head's K/V (L2-aligned). Longest blocks dispatch first.
//  - schedule stays R7-form: prefetch at loop top, single __syncthreads per iter.

typedef __attribute__((ext_vector_type(8))) short short8;
typedef __attribute__((ext_vector_type(4))) float f32x4;

#define MFMA_B16(a, b, c) __builtin_amdgcn_mfma_f32_16x16x32_bf16(a, b, c, 0, 0, 0)

#if __has_builtin(__builtin_amdgcn_exp2f)
#define EXP2(x) __builtin_amdgcn_exp2f(x)
#else
#define EXP2(x) exp2f(x)
#endif

static __device__ __forceinline__ unsigned short f2bf(float f) {
    union { float f; unsigned int u; } v;
    v.f = f;
    unsigned int r = (v.u + 0x7fffu + ((v.u >> 16) & 1u)) >> 16;
    return (unsigned short)r;
}

static __device__ __forceinline__ unsigned int pk_bf16(float a, float b) {
#if __has_builtin(__builtin_amdgcn_cvt_pk_bf16_f32)
    typedef __bf16 bf2 __attribute__((ext_vector_type(2)));
    union { bf2 v; unsigned int u; } c;
    c.v = __builtin_amdgcn_cvt_pk_bf16_f32(a, b);
    return c.u;
#else
    return (unsigned int)f2bf(a) | ((unsigned int)f2bf(b) << 16);
#endif
}

static __device__ __forceinline__ void gl_lds16(const void* g, void* l) {
    __builtin_amdgcn_global_load_lds(
        (const __attribute__((address_space(1))) unsigned int*)g,
        (__attribute__((address_space(3))) unsigned int*)l, 16, 0, 0);
}

// ---------------- fused prep: convert x + transpose both weights ----------------
__global__ __launch_bounds__(256) void prep_kernel(const float4* __restrict__ x,
                                                   ushort4* __restrict__ xb,
                                                   const float* __restrict__ wqkv,
                                                   unsigned short* __restrict__ wqkvT,
                                                   const float* __restrict__ wproj,
                                                   unsigned short* __restrict__ wprojT) {
    const int bid = blockIdx.x;
    if (bid < 4096) {
        int i = bid * 256 + threadIdx.x;
        float4 v = x[i];
        ushort4 o;
        o.x = f2bf(v.x); o.y = f2bf(v.y); o.z = f2bf(v.z); o.w = f2bf(v.w);
        xb[i] = o;
        return;
    }
    __shared__ float t[32][33];
    const float* in;
    unsigned short* out;
    int R, C, bx, by;
    if (bid < 4096 + 3072) {
        int g = bid - 4096;
        in = wqkv; out = wqkvT; R = 1024; C = 3072;
        bx = g % 96; by = g / 96;
    } else {
        int g = bid - 7168;
        in = wproj; out = wprojT; R = 1024; C = 1024;
        bx = g & 31; by = g >> 5;
    }
    const int c0 = bx * 32, r0 = by * 32;
    const int xx = threadIdx.x & 31, yy0 = threadIdx.x >> 5;
    #pragma unroll
    for (int yy = yy0; yy < 32; yy += 8)
        t[yy][xx] = in[(size_t)(r0 + yy) * C + (c0 + xx)];
    __syncthreads();
    #pragma unroll
    for (int yy = yy0; yy < 32; yy += 8)
        out[(size_t)(c0 + yy) * R + (r0 + xx)] = f2bf(t[xx][yy]);
}

// ---------------- QKV GEMM: C[4096x3072] = A * Bt^T ----------------
// blockIdx.x 0..7 = Q (swapped MFMA, scaled), 8..15 = K (swapped), 16..23 = V (unswapped,
// direct b64 stores to vT [bh][d][s]).
__global__ __launch_bounds__(256) void gemm_qkv_kernel(const unsigned short* __restrict__ A,
                                                       const unsigned short* __restrict__ Bt,
                                                       const float* __restrict__ bias,
                                                       unsigned short* __restrict__ q,
                                                       unsigned short* __restrict__ k,
                                                       unsigned short* __restrict__ vT) {
    __shared__ unsigned short As[128 * 64];
    __shared__ unsigned short Bs[128 * 64];
    const int tid = threadIdx.x;
    const int lane = tid & 63, wave = tid >> 6;
    const int l15 = lane & 15, quad = lane >> 4;
    const int wm = wave >> 1, wn = wave & 1;
    const int row0 = blockIdx.y * 128, col0 = blockIdx.x * 128;
    const int K = 1024;
    const bool isV = (blockIdx.x >= 16);

    int srow[4], scol[4], sdst[4];
    #pragma unroll
    for (int h = 0; h < 4; ++h) {
        int D = h * 256 + wave * 64 + lane;
        srow[h] = D >> 3;
        scol[h] = ((D & 7) ^ (srow[h] & 7)) * 8;
        sdst[h] = (h * 256 + wave * 64) * 8;
    }

    f32x4 acc[4][4] = {};

    for (int kt = 0; kt < K; kt += 64) {
        #pragma unroll
        for (int h = 0; h < 4; ++h) {
            gl_lds16(&A[(size_t)(row0 + srow[h]) * K + kt + scol[h]], &As[sdst[h]]);
            gl_lds16(&Bt[(size_t)(col0 + srow[h]) * K + kt + scol[h]], &Bs[sdst[h]]);
        }
        __syncthreads();
        #pragma unroll
        for (int kk = 0; kk < 2; ++kk) {
            short8 af[4], bf[4];
            #pragma unroll
            for (int i = 0; i < 4; ++i) {
                int r = wm * 64 + i * 16 + l15;
                af[i] = *(const short8*)&As[r * 64 + (((kk * 4 + quad) ^ (r & 7)) * 8)];
            }
            #pragma unroll
            for (int j = 0; j < 4; ++j) {
                int r = wn * 64 + j * 16 + l15;
                bf[j] = *(const short8*)&Bs[r * 64 + (((kk * 4 + quad) ^ (r & 7)) * 8)];
            }
            if (isV) {
                #pragma unroll
                for (int i = 0; i < 4; ++i)
                    #pragma unroll
                    for (int j = 0; j < 4; ++j)
                        acc[i][j] = MFMA_B16(af[i], bf[j], acc[i][j]);  // C
            } else {
                #pragma unroll
                for (int i = 0; i < 4; ++i)
                    #pragma unroll
                    for (int j = 0; j < 4; ++j)
                        acc[i][j] = MFMA_B16(bf[j], af[i], acc[i][j]);  // C^T
            }
        }
        __syncthreads();
    }

    const int b = row0 >> 11;
    const int s0 = row0 & 2047;
    const float* bb = bias + col0 + wn * 64;

    if (!isV) {
        // C^T: lane holds d = j*16 + quad*4 + {0..3} for s = wm*64 + i*16 + l15
        const int which = blockIdx.x >> 3;  // 0=Q, 1=K
        unsigned short* dst = which ? k : q;
        const float scale = which ? 1.0f : 0.1803368867f;  // 1/8 * log2(e) for Q
        const int hh = ((blockIdx.x & 7) << 1) + wn;
        #pragma unroll
        for (int i = 0; i < 4; ++i) {
            const int s = s0 + wm * 64 + i * 16 + l15;
            unsigned short* drow = dst + ((size_t)((b * 16 + hh) * 2048 + s)) * 64;
            #pragma unroll
            for (int j = 0; j < 4; ++j) {
                float4 b4 = ((const float4*)bb)[j * 4 + quad];
                uint2 pv;
                pv.x = pk_bf16((acc[i][j][0] + b4.x) * scale, (acc[i][j][1] + b4.y) * scale);
                pv.y = pk_bf16((acc[i][j][2] + b4.z) * scale, (acc[i][j][3] + b4.w) * scale);
                *(uint2*)&drow[j * 16 + quad * 4] = pv;
            }
        }
    } else {
        // C: lane holds s = wm*64 + i*16 + quad*4 + {0..3} for d = j*16 + l15
        const int hh = ((blockIdx.x - 16) << 1) + wn;
        #pragma unroll
        for (int j = 0; j < 4; ++j) {
            const int d = j * 16 + l15;
            const float bv = bb[d];
            unsigned short* drow = vT + ((size_t)((b * 16 + hh) * 64 + d)) * 2048 + s0;
            #pragma unroll
            for (int i = 0; i < 4; ++i) {
                uint2 pv;
                pv.x = pk_bf16(acc[i][j][0] + bv, acc[i][j][1] + bv);
                pv.y = pk_bf16(acc[i][j][2] + bv, acc[i][j][3] + bv);
                *(uint2*)&drow[wm * 64 + i * 16 + quad * 4] = pv;
            }
        }
    }
}

// ---------------- proj GEMM: out[4096x1024] fp32 = A * Bt^T + bias ----------------
// Swapped MFMA -> C^T in registers -> float4 stores.
__global__ __launch_bounds__(256) void gemm_proj_kernel(const unsigned short* __restrict__ A,
                                                        const unsigned short* __restrict__ Bt,
                                                        const float* __restrict__ bias,
                                                        float* __restrict__ out) {
    __shared__ unsigned short As[128 * 64];
    __shared__ unsigned short Bs[64 * 64];
    const int tid = threadIdx.x;
    const int lane = tid & 63, wave = tid >> 6;
    const int l15 = lane & 15, quad = lane >> 4;
    const int wm = wave >> 1, wn = wave & 1;
    const int row0 = blockIdx.y * 128, col0 = blockIdx.x * 64;
    const int K = 1024;

    int srow[4], scol[4], sdst[4];
    #pragma unroll
    for (int h = 0; h < 4; ++h) {
        int D = h * 256 + wave * 64 + lane;
        srow[h] = D >> 3;
        scol[h] = ((D & 7) ^ (srow[h] & 7)) * 8;
        sdst[h] = (h * 256 + wave * 64) * 8;
    }

    f32x4 acc[4][2] = {};

    for (int kt = 0; kt < K; kt += 64) {
        #pragma unroll
        for (int h = 0; h < 4; ++h)
            gl_lds16(&A[(size_t)(row0 + srow[h]) * K + kt + scol[h]], &As[sdst[h]]);
        #pragma unroll
        for (int h = 0; h < 2; ++h)
            gl_lds16(&Bt[(size_t)(col0 + srow[h]) * K + kt + scol[h]], &Bs[sdst[h]]);
        __syncthreads();
        #pragma unroll
        for (int kk = 0; kk < 2; ++kk) {
            short8 af[4], bf[2];
            #pragma unroll
            for (int i = 0; i < 4; ++i) {
                int r = wm * 64 + i * 16 + l15;
                af[i] = *(const short8*)&As[r * 64 + (((kk * 4 + quad) ^ (r & 7)) * 8)];
            }
            #pragma unroll
            for (int j = 0; j < 2; ++j) {
                int r = wn * 32 + j * 16 + l15;
                bf[j] = *(const short8*)&Bs[r * 64 + (((kk * 4 + quad) ^ (r & 7)) * 8)];
            }
            #pragma unroll
            for (int i = 0; i < 4; ++i)
                #pragma unroll
                for (int j = 0; j < 2; ++j)
                    acc[i][j] = MFMA_B16(bf[j], af[i], acc[i][j]);  // C^T
        }
        __syncthreads();
    }

    const float* bb = bias + col0 + wn * 32;
    #pragma unroll
    for (int i = 0; i < 4; ++i) {
        const int row = row0 + wm * 64 + i * 16 + l15;
        #pragma unroll
        for (int j = 0; j < 2; ++j) {
            float4 b4 = ((const float4*)bb)[j * 4 + quad];
            float4 ov;
            ov.x = acc[i][j][0] + b4.x;
            ov.y = acc[i][j][1] + b4.y;
            ov.z = acc[i][j][2] + b4.z;
            ov.w = acc[i][j][3] + b4.w;
            *(float4*)&out[(size_t)row * 1024 + col0 + wn * 32 + j * 16 + quad * 4] = ov;
        }
    }
}

// ---------------- flash attention (R10: adjacent-pair 512-thread blocks) ----------------
// smem layout (shorts): [0..4095] Ks0 | [4096..8191] Ks1 | [8192..12287] Vs0
//                       [12288..16383] Vs1 | [16384..24575] Pw[8][1024]
__global__ __launch_bounds__(512) void attn_kernel(const unsigned short* __restrict__ Q,
                                                   const unsigned short* __restrict__ Kg,
                                                   const unsigned short* __restrict__ Vt,
                                                   const int* __restrict__ idx,
                                                   const float* __restrict__ weight,
                                                   const int* __restrict__ forcing,
                                                   unsigned short* __restrict__ O) {
    __shared__ unsigned short smem[24576];

    const int tid = threadIdx.x;
    const int lane = tid & 63, wave = tid >> 6;
    const int l15 = lane & 15, quad = lane >> 4;
    const int bid = blockIdx.x;
    // R10 mapping: bid<256 = long blocks (p=8..15), bid>=256 = complements (p=7..0)
    // with the same rem -> the CU hosting bids {c, c+256} runs 2p+2 + (2p'+2) = 34
    // iterations total and both blocks stream the same head's K/V.
    // rem&7 ~ XCD -> 4 heads per XCD (2MB K/V, L2-resident).
    const int qh = bid >> 8;          // 0 = long half, 1 = short half
    const int rem = bid & 255;
    const int xcd = rem & 7;
    const int head = (rem >> 3) & 3;
    const int g2 = rem >> 5;          // 0..7
    const int p = qh ? (7 - g2) : (8 + g2);
    const int bh = xcd * 4 + head;
    const int tA = 2 * p + 1, tB = 2 * p;  // adjacent q-tiles
    const int b = bh >> 4, hh = bh & 15;
    const unsigned short* Qb = Q + (size_t)bh * 2048 * 64;
    const unsigned short* Kh = Kg + (size_t)bh * 2048 * 64;
    const unsigned short* Vh = Vt + (size_t)bh * 2048 * 64;

    const int idxb = idx[b];
    const float lw = (forcing[0] != 0) ? __log2f(weight[0]) : 0.0f;

    // this wave's q-tile: waves 0-3 -> tA, waves 4-7 -> tB (idle only on last tile)
    const int wq = (wave < 4) ? tA : tB;
    const int wg = wave & 3;
    const int q0 = wq * 64 + wg * 16;
    const int qrow = q0 + l15;
    const int nkb = tA + 1;    // block-level k-tile count (= 2p+2)
    const int nkbw = wq + 1;   // this wave's active k-tile count

    // staging: 512 threads, 1 K-chunk + 1 V-chunk (16B) each per tile
    const int rS = tid >> 3;
    const int cS8 = ((tid & 7) ^ (rS & 7)) * 8;

    short8 aq0 = *(const short8*)&Qb[(q0 + l15) * 64 + quad * 8];
    short8 aq1 = *(const short8*)&Qb[(q0 + l15) * 64 + 32 + quad * 8];

    const short8 ones8 = {0x3F80, 0x3F80, 0x3F80, 0x3F80, 0x3F80, 0x3F80, 0x3F80, 0x3F80};

    f32x4 o[4] = {};
    f32x4 lsum = {};

    // prologue: stage tile 0
    gl_lds16(Kh + (size_t)rS * 64 + cS8,   &smem[tid * 8]);
    gl_lds16(Vh + (size_t)rS * 2048 + cS8, &smem[8192 + tid * 8]);
    __syncthreads();

    unsigned short* const pwb = &smem[16384 + wave * 1024];
    const int pwr = l15 * 64;
    const int pa7 = l15 & 7;

    for (int kb = 0; kb < nkb; ++kb) {
        const int cur = kb & 1;
        const int kbase = kb * 64;
        if (kb + 1 < nkb) {
            const int nb = kbase + 64;
            gl_lds16(Kh + (size_t)(nb + rS) * 64 + cS8,      &smem[(cur ^ 1) * 4096 + tid * 8]);
            gl_lds16(Vh + (size_t)rS * 2048 + nb + cS8,      &smem[8192 + (cur ^ 1) * 4096 + tid * 8]);
        }

        if (kb < nkbw) {
            const unsigned short* KsP = &smem[cur * 4096];
            const unsigned short* VsP = &smem[8192 + cur * 4096];

            const bool fullF = (kbase >= idxb);
            const bool bndF = (!fullF) && (kbase + 63 >= idxb);
            const float zu = fullF ? lw : 0.0f;

            f32x4 sT[4];
            #pragma unroll
            for (int kt = 0; kt < 4; ++kt) {
                const int row = kt * 16 + l15;
                short8 k0 = *(const short8*)&KsP[row * 64 + ((quad ^ (row & 7)) * 8)];
                short8 k1 = *(const short8*)&KsP[row * 64 + (((4 + quad) ^ (row & 7)) * 8)];
                f32x4 z;
                if (!bndF) {
                    z[0] = zu; z[1] = zu; z[2] = zu; z[3] = zu;
                } else {
                    #pragma unroll
                    for (int r = 0; r < 4; ++r)
                        z[r] = (kbase + kt * 16 + quad * 4 + r >= idxb) ? lw : 0.0f;
                }
                z = MFMA_B16(k0, aq0, z);
                z = MFMA_B16(k1, aq1, z);
                sT[kt] = z;
            }

            if (kb == wq) {
                #pragma unroll
                for (int kt = 0; kt < 4; ++kt)
                    #pragma unroll
                    for (int r = 0; r < 4; ++r)
                        if (kbase + kt * 16 + quad * 4 + r > qrow) sT[kt][r] = -3.0e38f;
            }

            #pragma unroll
            for (int kt = 0; kt < 4; ++kt)
                #pragma unroll
                for (int r = 0; r < 4; ++r)
                    sT[kt][r] = EXP2(sT[kt][r]);

            #pragma unroll
            for (int kt = 0; kt < 4; ++kt) {
                unsigned int* pw = (unsigned int*)&pwb[pwr +
                    (((kt * 2 + (quad >> 1)) ^ pa7) * 8) + (quad & 1) * 4];
                pw[0] = pk_bf16(sT[kt][0], sT[kt][1]);
                pw[1] = pk_bf16(sT[kt][2], sT[kt][3]);
            }

            short8 bp0 = *(const short8*)&pwb[pwr + ((quad ^ pa7) * 8)];
            short8 bp1 = *(const short8*)&pwb[pwr + (((4 + quad) ^ pa7) * 8)];

            lsum = MFMA_B16(ones8, bp0, lsum);
            lsum = MFMA_B16(ones8, bp1, lsum);

            #pragma unroll
            for (int dt = 0; dt < 4; ++dt) {
                const int row = dt * 16 + l15;
                short8 vf0 = *(const short8*)&VsP[row * 64 + ((quad ^ (row & 7)) * 8)];
                short8 vf1 = *(const short8*)&VsP[row * 64 + (((4 + quad) ^ (row & 7)) * 8)];
                f32x4 oo = o[dt];
                oo = MFMA_B16(vf0, bp0, oo);
                oo = MFMA_B16(vf1, bp1, oo);
                o[dt] = oo;
            }
        }

        __syncthreads();
    }

    // epilogue: per-wave transpose through LDS scratch (8 waves x 1152 shorts <= 24576)
    const float inv = 1.0f / lsum[0];
    unsigned short* sc = &smem[wave * 1152];
    #pragma unroll
    for (int dt = 0; dt < 4; ++dt)
        #pragma unroll
        for (int r = 0; r < 4; ++r)
            sc[l15 * 72 + dt * 16 + quad * 4 + r] = f2bf(o[dt][r] * inv);
    const size_t rowoff = ((size_t)(b * 2048 + q0 + l15)) * 1024 + hh * 64;
    #pragma unroll
    for (int h = 0; h < 2; ++h) {
        short8 v8 = *(const short8*)&sc[l15 * 72 + quad * 16 + h * 8];
        *(short8*)&O[rowoff + quad * 16 + h * 8] = v8;
    }
}

extern "C" void kernel_launch(void* const* d_in, const int* in_sizes, int n_in,
                              void* d_out, int out_size, void* d_ws, size_t ws_size,
                              hipStream_t stream) {
    const float* x        = (const float*)d_in[0];
    const int*   idx      = (const int*)d_in[1];
    const float* weight   = (const float*)d_in[2];
    const int*   forcing  = (const int*)d_in[3];
    const float* w_qkv    = (const float*)d_in[4];
    const float* b_qkv    = (const float*)d_in[5];
    const float* w_proj   = (const float*)d_in[6];
    const float* b_proj   = (const float*)d_in[7];
    float* out = (float*)d_out;

    char* ws = (char*)d_ws;
    unsigned short* xb      = (unsigned short*)(ws);              // 8 MB (reused: attn_out)
    unsigned short* wqkvT   = (unsigned short*)(ws + 8388608);    // 6 MB
    unsigned short* wprojT  = (unsigned short*)(ws + 14680064);   // 2 MB
    unsigned short* qbuf    = (unsigned short*)(ws + 16777216);   // 8 MB
    unsigned short* kbuf    = (unsigned short*)(ws + 25165824);   // 8 MB
    unsigned short* vTbuf   = (unsigned short*)(ws + 33554432);   // 8 MB
    unsigned short* attn_out = xb;  // xb dead after gemm_qkv

    prep_kernel<<<8192, 256, 0, stream>>>((const float4*)x, (ushort4*)xb,
                                          w_qkv, wqkvT, w_proj, wprojT);
    gemm_qkv_kernel<<<dim3(24, 32), 256, 0, stream>>>(xb, wqkvT, b_qkv, qbuf, kbuf, vTbuf);
    attn_kernel<<<512, 512, 0, stream>>>(qbuf, kbuf, vTbuf, idx, weight, forcing, attn_out);
    gemm_proj_kernel<<<dim3(16, 32), 256, 0, stream>>>(attn_out, wprojT, b_proj, out);
}